// Round 1
// baseline (402.671 us; speedup 1.0000x reference)
//
#include <hip/hip_runtime.h>

#define BATCH   256
#define DIMS    64
#define LEVELS  100
#define HVD     10000

// ---------------------------------------------------------------------------
// Kernel 1: encode (unnormalized) — out[b,h] = sum_d (1-a)*base[d,lo,h] + a*base[d,hi,h]
// grid: (BATCH/4 b-tiles [fastest, for L2 sharing of h-tile], ceil(HVD/256) h-tiles)
// block: 256 threads = 4 waves; wave w owns batch b_tile*4+w, lanes cover 256 h cols (float4 each)
// ---------------------------------------------------------------------------
__global__ __launch_bounds__(256) void encode_kernel(
    const float* __restrict__ x,
    const float* __restrict__ base,
    float* __restrict__ out)
{
    __shared__ int   s_off_lo[256];   // (d*LEVELS+lo)*HVD, per (b_local, d)
    __shared__ int   s_off_hi[256];
    __shared__ float s_alpha[256];

    const int tid    = threadIdx.x;
    const int b_tile = blockIdx.x;          // 0..63
    const int h0     = blockIdx.y * 256;    // h-tile start

    // Precompute interpolation params: one thread per (b_local, d) entry.
    {
        const int bl = tid >> 6;            // 0..3
        const int d  = tid & 63;            // 0..63
        const int b  = b_tile * 4 + bl;
        float xv = x[b * DIMS + d];
        float xn = xv * (float)(LEVELS - 1);
        xn = fminf(fmaxf(xn, 0.0f), (float)(LEVELS - 1));
        float fl = floorf(xn);
        int   lo = (int)fl;
        int   hi = lo + 1; if (hi > LEVELS - 1) hi = LEVELS - 1;
        s_off_lo[tid] = (d * LEVELS + lo) * HVD;
        s_off_hi[tid] = (d * LEVELS + hi) * HVD;
        s_alpha[tid]  = xn - fl;
    }
    __syncthreads();

    const int bl   = tid >> 6;              // wave id == b_local
    const int lane = tid & 63;
    const int h    = h0 + lane * 4;
    if (h >= HVD) return;                   // tail h-tile (h0=9984): lanes >=4 idle
    const int b    = b_tile * 4 + bl;

    const int ebase = bl * 64;
    float4 acc = make_float4(0.f, 0.f, 0.f, 0.f);

    #pragma unroll 8
    for (int d = 0; d < DIMS; ++d) {
        const int   off_lo = s_off_lo[ebase + d];   // wave-uniform LDS broadcast
        const int   off_hi = s_off_hi[ebase + d];
        const float a      = s_alpha[ebase + d];
        const float wl     = 1.0f - a;
        float4 vlo = *(const float4*)(base + off_lo + h);  // 1 KB coalesced per wave
        float4 vhi = *(const float4*)(base + off_hi + h);
        acc.x += wl * vlo.x + a * vhi.x;
        acc.y += wl * vlo.y + a * vhi.y;
        acc.z += wl * vlo.z + a * vhi.z;
        acc.w += wl * vlo.w + a * vhi.w;
    }

    *(float4*)(out + b * HVD + h) = acc;
}

// ---------------------------------------------------------------------------
// Kernel 2: in-place row L2 normalization. One block per batch row.
// ---------------------------------------------------------------------------
__global__ __launch_bounds__(256) void normalize_kernel(float* __restrict__ out)
{
    const int b   = blockIdx.x;
    const int tid = threadIdx.x;
    float* row = out + b * HVD;
    const float4* row4 = (const float4*)row;

    float ss = 0.f;
    for (int i = tid; i < HVD / 4; i += 256) {
        float4 v = row4[i];
        ss += v.x * v.x + v.y * v.y + v.z * v.z + v.w * v.w;
    }

    __shared__ float red[256];
    red[tid] = ss;
    __syncthreads();
    #pragma unroll
    for (int s = 128; s > 0; s >>= 1) {
        if (tid < s) red[tid] += red[tid + s];
        __syncthreads();
    }
    const float inv = rsqrtf(red[0]);

    for (int i = tid; i < HVD / 4; i += 256) {
        float4 v = ((float4*)row)[i];
        v.x *= inv; v.y *= inv; v.z *= inv; v.w *= inv;
        ((float4*)row)[i] = v;
    }
}

extern "C" void kernel_launch(void* const* d_in, const int* in_sizes, int n_in,
                              void* d_out, int out_size, void* d_ws, size_t ws_size,
                              hipStream_t stream)
{
    const float* x    = (const float*)d_in[0];   // (256, 64)
    const float* base = (const float*)d_in[1];   // (64, 100, 10000)
    float*       out  = (float*)d_out;           // (256, 10000)

    dim3 grid(BATCH / 4, (HVD + 255) / 256);     // b-tiles fastest -> h-tile L2 sharing
    encode_kernel<<<grid, 256, 0, stream>>>(x, base, out);
    normalize_kernel<<<BATCH, 256, 0, stream>>>(out);
}